// Round 13
// baseline (771.553 us; speedup 1.0000x reference)
//
#include <hip/hip_runtime.h>
#include <hip/hip_bf16.h>
#include <math.h>

// Problem constants (fixed by the reference)
#define NN 50000
#define EE 400000
#define TT 4
#define DIN 64
#define DD 128
#define BB 64
#define STEPS 8
#define KAGG 512    // 4 types x 128 (counts handled in epilogue via Cmat)
#define NGATES 512  // [r_sum, z_sum, i_n, h_n]
#define NBIN (4 * NN)             // (dst, etype) bins
#define NBLK ((NBIN + 255) / 256) // 782 scan blocks
#define MT64 ((NN + 63) / 64)     // 782 step blocks
#define W2F_N (20 * 12288)        // fragment-ordered W2: [kc][gb][wave][lane][8]

typedef __attribute__((ext_vector_type(8))) short bf16x8;
typedef __attribute__((ext_vector_type(4))) float f32x4;
typedef __attribute__((address_space(3))) void lds_void;
typedef __attribute__((address_space(1))) void glob_void;

__device__ inline float bf2f(__hip_bfloat16 x) { return __bfloat162float(x); }

// exact bf16(bit pattern in short) -> f32, value-based (vector elements have no address)
__device__ inline float s2f(short s) {
    unsigned int u = ((unsigned int)(unsigned short)s) << 16;
    float f;
    __builtin_memcpy(&f, &u, 4);
    return f;
}

// ---------------------------------------------------------------- init (zero-pad 64->128)
__global__ void k_init_h(const float* __restrict__ feat, float* __restrict__ h1,
                         __hip_bfloat16* __restrict__ hb) {
    int idx = blockIdx.x * blockDim.x + threadIdx.x;
    if (idx >= NN * DD) return;
    int v = idx >> 7, d = idx & 127;
    float val = (d < DIN) ? feat[v * DIN + d] : 0.0f;
    h1[idx] = val;
    hb[idx] = __float2bfloat16(val);
}

__global__ void k_zero_i32(int* __restrict__ p, int n) {
    int idx = blockIdx.x * blockDim.x + threadIdx.x;
    if (idx < n) p[idx] = 0;
}
__global__ void k_zero_f32(float* __restrict__ p, int n) {
    int idx = blockIdx.x * blockDim.x + threadIdx.x;
    if (idx < n) p[idx] = 0.0f;
}

// ---------------------------------------------------------------- CSR build by (dst,type)
__global__ void k_hist(const int* __restrict__ dst, const int* __restrict__ etype,
                       int* __restrict__ deg2) {
    int e = blockIdx.x * blockDim.x + threadIdx.x;
    if (e < EE) atomicAdd(&deg2[dst[e] * 4 + etype[e]], 1);
}

__global__ __launch_bounds__(256) void k_scan_bsum(const int* __restrict__ deg2,
                                                   int* __restrict__ bsum) {
    __shared__ int red[256];
    int tid = threadIdx.x;
    int i = blockIdx.x * 256 + tid;
    int v = (i < NBIN) ? deg2[i] : 0;
    red[tid] = v;
    __syncthreads();
#pragma unroll
    for (int s = 128; s > 0; s >>= 1) {
        if (tid < s) red[tid] += red[tid + s];
        __syncthreads();
    }
    if (tid == 0) bsum[blockIdx.x] = red[0];
}

__global__ __launch_bounds__(1024) void k_scan_boff(const int* __restrict__ bsum,
                                                    int* __restrict__ boff) {
    __shared__ int s[1024];
    int tid = threadIdx.x;
    int v = (tid < NBLK) ? bsum[tid] : 0;
    s[tid] = v;
    __syncthreads();
    for (int d = 1; d < 1024; d <<= 1) {
        int t = (tid >= d) ? s[tid - d] : 0;
        __syncthreads();
        s[tid] += t;
        __syncthreads();
    }
    if (tid < NBLK) boff[tid] = s[tid] - v;  // exclusive
}

__global__ __launch_bounds__(256) void k_scan_final(const int* __restrict__ deg2,
                                                    const int* __restrict__ boff,
                                                    int* __restrict__ off2,
                                                    int* __restrict__ cursor) {
    __shared__ int s[256];
    int tid = threadIdx.x;
    int i = blockIdx.x * 256 + tid;
    int v = (i < NBIN) ? deg2[i] : 0;
    s[tid] = v;
    __syncthreads();
#pragma unroll
    for (int d = 1; d < 256; d <<= 1) {
        int t = (tid >= d) ? s[tid - d] : 0;
        __syncthreads();
        s[tid] += t;
        __syncthreads();
    }
    int excl = boff[blockIdx.x] + s[tid] - v;
    if (i < NBIN) {
        off2[i] = excl;
        cursor[i] = excl;
        if (i == NBIN - 1) off2[NBIN] = excl + v;  // == EE
    }
}

__global__ void k_fill(const int* __restrict__ dst, const int* __restrict__ src,
                       const int* __restrict__ etype, int* __restrict__ cursor,
                       int* __restrict__ csr_src) {
    int e = blockIdx.x * blockDim.x + threadIdx.x;
    if (e < EE) {
        int pos = atomicAdd(&cursor[dst[e] * 4 + etype[e]], 1);
        csr_src[pos] = src[e];
    }
}

// ---------------------------------------------------------------- weight prep (once/call)
// Fragment-ordered composed weights W2f[kc 0..19][gb 0..2][wave 0..7][lane 0..63][8] bf16:
//   kc<16 (g-part): k = kc*32+kin in 0..511, n = gb*128 + wave*16 + (lane&15) (r,z,i_n),
//                   value = Sum_e Wm[t][kd][e]*wih[e][n], t=k>>7, kd=k&127
//   kc>=16 (h-part): kh = (kc-16)*32+kin, n = {gb<2: gb*128, else h_n} + ..., value = w_hh
// Cmat[4][384]: C[t][n] = Sum_e b_msg[t][e]*wih[e][n]  (count contribution, epilogue).
// bias512: 0..255 bih+bhh (r,z); 256..383 bih (i_n); 384..511 bhh[256..384] (h_n).
__global__ void k_prep_w2f(const float* __restrict__ Wm, const float* __restrict__ bm,
                           const float* __restrict__ wih, const float* __restrict__ whh,
                           const float* __restrict__ bih, const float* __restrict__ bhh,
                           __hip_bfloat16* __restrict__ W2f, float* __restrict__ Cmat,
                           float* __restrict__ bias512) {
    int idx = blockIdx.x * blockDim.x + threadIdx.x;
    if (idx < W2F_N) {
        int kc = idx / 12288;
        int r1 = idx % 12288;
        int gb = r1 >> 12;
        int r2 = r1 & 4095;
        int w = r2 >> 9;
        int r3 = r2 & 511;
        int l = r3 >> 3;
        int j = r3 & 7;
        int npart = w * 16 + (l & 15);
        int kin = ((l >> 4) << 3) + j;
        float v;
        if (kc < 16) {
            int k = kc * 32 + kin;        // 0..511
            int n = gb * 128 + npart;     // 0..383: r, z, i_n
            int t = k >> 7, kd = k & 127;
            const float* wr = Wm + (t << 14) + (kd << 7);
            float s = 0.0f;
#pragma unroll 4
            for (int e = 0; e < 128; ++e) s += wr[e] * wih[e * 384 + n];
            v = s;
        } else {
            int kh = (kc - 16) * 32 + kin;                         // 0..127
            int nlog = (gb < 2) ? gb * 128 + npart : 384 + npart;  // r,z,h_n
            int col = (nlog < 256) ? nlog : nlog - 128;            // w_hh col
            v = whh[kh * 384 + col];
        }
        W2f[idx] = __float2bfloat16(v);
        return;
    }
    int j2 = idx - W2F_N;
    if (j2 < 4 * 384) {
        int t = j2 / 384, n = j2 % 384;
        const float* br = bm + t * 128;
        float s = 0.0f;
#pragma unroll 4
        for (int e = 0; e < 128; ++e) s += br[e] * wih[e * 384 + n];
        Cmat[j2] = s;
        return;
    }
    int b = j2 - 4 * 384;
    if (b < NGATES) {
        float v;
        if (b < 256) v = bih[b] + bhh[b];
        else if (b < 384) v = bih[b];
        else v = bhh[b - 128];
        bias512[b] = v;
    }
}

// ---------------------------------------------------------------- per-type aggregation v3
// One WAVE per node; 4x 16-lane GROUPS walk the node's 4 type-lists CONCURRENTLY.
// Gather-chain collapse: lane sub loads csr_src[base+sub] (16 indices per instr),
// __shfl broadcasts index r to its group -> all h-row loads are address-independent
// and issue back-to-back (chain depth ~2 latencies instead of cnt).
__global__ __launch_bounds__(256) void k_agg(const __hip_bfloat16* __restrict__ hb,
                                             const int* __restrict__ off2,
                                             const int* __restrict__ csr_src,
                                             __hip_bfloat16* __restrict__ g) {
    const int node = (blockIdx.x * blockDim.x + threadIdx.x) >> 6;
    const int lane = threadIdx.x & 63;
    if (node >= NN) return;
    const int t = lane >> 4;    // group = etype
    const int sub = lane & 15;  // 8 dims per lane
    const int gbase = lane & 48;  // group's lane base for shfl
    const int p0 = off2[4 * node + t];
    const int p1 = off2[4 * node + t + 1];
    float a[8];
#pragma unroll
    for (int j = 0; j < 8; ++j) a[j] = 0.0f;
    for (int base = p0; base < p1; base += 16) {
        int cnt = p1 - base;
        if (cnt > 16) cnt = 16;
        int idxv = (sub < cnt) ? csr_src[base + sub] : 0;
        int r = 0;
        for (; r + 1 < cnt; r += 2) {
            int s0 = __shfl(idxv, gbase + r);
            int s1 = __shfl(idxv, gbase + r + 1);
            bf16x8 v0 = *(const bf16x8*)(hb + (size_t)s0 * DD + sub * 8);
            bf16x8 v1 = *(const bf16x8*)(hb + (size_t)s1 * DD + sub * 8);
#pragma unroll
            for (int j = 0; j < 8; ++j) a[j] += s2f(v0[j]) + s2f(v1[j]);
        }
        if (r < cnt) {
            int s0 = __shfl(idxv, gbase + r);
            bf16x8 v0 = *(const bf16x8*)(hb + (size_t)s0 * DD + sub * 8);
#pragma unroll
            for (int j = 0; j < 8; ++j) a[j] += s2f(v0[j]);
        }
    }
    bf16x8 o;
#pragma unroll
    for (int j = 0; j < 8; ++j) {
        __hip_bfloat16 b = __float2bfloat16(a[j]);
        o[j] = *(short*)&b;
    }
    *(bf16x8*)(g + (size_t)node * KAGG + t * 128 + sub * 8) = o;
}

// ---------------------------------------------------------------- fused step kernel (v8)
// A through LDS (2-buffer ping-pong, global_load_lds + swizzle). B direct
// global->register from fragment-ordered W2f (no inter-wave B sharing -> no LDS).
// 20 chunks (16 g + 4 h); counts contribution via Cmat in the epilogue.
__global__ __launch_bounds__(512, 4) void k_step(const __hip_bfloat16* __restrict__ g,
                                                 const __hip_bfloat16* __restrict__ W2f,
                                                 const float* __restrict__ Cmat,
                                                 const float* __restrict__ bias512,
                                                 const int* __restrict__ off2,
                                                 const __hip_bfloat16* __restrict__ hbi,
                                                 __hip_bfloat16* __restrict__ hbo) {
    __shared__ __align__(16) short As[2][64 * 32];  // 2 x 4 KB ping-pong
    __shared__ __align__(16) short Ht[64 * 132];    // 16.9 KB epilogue stage
    const int tid = threadIdx.x;
    const int lane = tid & 63;
    const int wave = tid >> 6;
    const int row0 = blockIdx.x * 64;
    const int quad = lane >> 4;
    const int m16 = lane & 15;
    const int koff = ((quad ^ ((m16 ^ (m16 >> 2)) & 3)) << 3);  // A swizzle (shorts)

    // A staging mapping (waves 0..3; slot = tid < 256)
    const int arow = tid >> 2;
    const int apart = (tid & 3) ^ ((arow ^ (arow >> 2)) & 3);
    int agrow = row0 + arow;
    if (agrow >= NN) agrow = NN - 1;
    const __hip_bfloat16* gA = g + (size_t)agrow * KAGG + apart * 8;
    const __hip_bfloat16* hA = hbi + (size_t)agrow * DD + apart * 8;
    const __hip_bfloat16* bw = W2f + ((size_t)(wave * 64 + lane)) * 8;  // own fragment base

    auto stage_A = [&](int kc) {
        if (wave < 4) {
            const glob_void* srcA = (kc < 16)
                                        ? (const glob_void*)(gA + kc * 32)
                                        : (const glob_void*)(hA + (kc - 16) * 32);
            __builtin_amdgcn_global_load_lds(srcA, (lds_void*)&As[kc & 1][(wave * 64) * 8],
                                             16, 0, 0);
        }
    };

    f32x4 acc[4][4];  // [row-tile][gate: r,z,in,hn]
#pragma unroll
    for (int rt = 0; rt < 4; ++rt)
#pragma unroll
        for (int c = 0; c < 4; ++c) acc[rt][c] = (f32x4){0.f, 0.f, 0.f, 0.f};

    stage_A(0);
    __syncthreads();

    for (int ki = 0; ki < 20; ++ki) {
        if (ki + 1 < 20) stage_A(ki + 1);

        // B: direct global->register, own contiguous 1KB fragments (L2-hot)
        const __hip_bfloat16* bp = bw + ki * 12288;
        bf16x8 b0 = *(const bf16x8*)(bp);
        bf16x8 b1 = *(const bf16x8*)(bp + 4096);
        bf16x8 b2 = *(const bf16x8*)(bp + 8192);

        bf16x8 af[4];
#pragma unroll
        for (int rt = 0; rt < 4; ++rt)
            af[rt] = *(const bf16x8*)&As[ki & 1][(rt * 16 + m16) * 32 + koff];
#pragma unroll
        for (int rt = 0; rt < 4; ++rt)
            acc[rt][0] = __builtin_amdgcn_mfma_f32_16x16x32_bf16(af[rt], b0, acc[rt][0], 0, 0, 0);
#pragma unroll
        for (int rt = 0; rt < 4; ++rt)
            acc[rt][1] = __builtin_amdgcn_mfma_f32_16x16x32_bf16(af[rt], b1, acc[rt][1], 0, 0, 0);
        if (ki < 16) {
#pragma unroll
            for (int rt = 0; rt < 4; ++rt)
                acc[rt][2] = __builtin_amdgcn_mfma_f32_16x16x32_bf16(af[rt], b2, acc[rt][2], 0, 0, 0);
        } else {
#pragma unroll
            for (int rt = 0; rt < 4; ++rt)
                acc[rt][3] = __builtin_amdgcn_mfma_f32_16x16x32_bf16(af[rt], b2, acc[rt][3], 0, 0, 0);
        }
        __syncthreads();  // drains stage_A(ki+1); As[ki&1] free for reuse next iter
    }

    // ---------------- epilogue: counts(Cmat) + GRU -> LDS (stride 132) -> store ----
    {
        const int d = wave * 16 + m16;
        const float brs = bias512[d];
        const float bzs = bias512[128 + d];
        const float bin_ = bias512[256 + d];
        const float bhn = bias512[384 + d];
        const float c0r = Cmat[d], c1r = Cmat[384 + d], c2r = Cmat[768 + d], c3r = Cmat[1152 + d];
        const float c0z = Cmat[128 + d], c1z = Cmat[512 + d], c2z = Cmat[896 + d], c3z = Cmat[1280 + d];
        const float c0n = Cmat[256 + d], c1n = Cmat[640 + d], c2n = Cmat[1024 + d], c3n = Cmat[1408 + d];
#pragma unroll
        for (int rt = 0; rt < 4; ++rt) {
#pragma unroll
            for (int j = 0; j < 4; ++j) {
                const int rowl = rt * 16 + quad * 4 + j;
                int grow = row0 + rowl;
                if (grow >= NN) grow = NN - 1;  // clamped; global store is guarded
                const int* o2 = off2 + 4 * grow;
                const float cnt0 = (float)(o2[1] - o2[0]);
                const float cnt1 = (float)(o2[2] - o2[1]);
                const float cnt2 = (float)(o2[3] - o2[2]);
                const float cnt3 = (float)(o2[4] - o2[3]);
                const float rs = acc[rt][0][j] + brs + cnt0 * c0r + cnt1 * c1r + cnt2 * c2r + cnt3 * c3r;
                const float zs = acc[rt][1][j] + bzs + cnt0 * c0z + cnt1 * c1z + cnt2 * c2z + cnt3 * c3z;
                const float inn = acc[rt][2][j] + bin_ + cnt0 * c0n + cnt1 * c1n + cnt2 * c2n + cnt3 * c3n;
                const float hnn = acc[rt][3][j] + bhn;
                const float rr = 1.0f / (1.0f + __expf(-rs));
                const float zz = 1.0f / (1.0f + __expf(-zs));
                const float ex = __expf(2.0f * (inn + rr * hnn));
                const float ng = 1.0f - 2.0f / (ex + 1.0f);  // tanh, overflow-safe
                const float hv = bf2f(hbi[(size_t)grow * DD + d]);
                const float o = (1.0f - zz) * ng + zz * hv;
                __hip_bfloat16 ob = __float2bfloat16(o);
                Ht[rowl * 132 + d] = *(short*)&ob;
            }
        }
    }
    __syncthreads();
    {
        // 512 threads x 32 B contiguous -> fully-coalesced full-line stores
        const int row = tid >> 3;
        const int col = (tid & 7) * 16;
        if (row0 + row < NN) {
            bf16x8 v0 = *(const bf16x8*)&Ht[row * 132 + col];
            bf16x8 v1 = *(const bf16x8*)&Ht[row * 132 + col + 8];
            __hip_bfloat16* dstp = hbo + (size_t)(row0 + row) * DD + col;
            *(bf16x8*)dstp = v0;
            *(bf16x8*)(dstp + 8) = v1;
        }
    }
}

// ---------------------------------------------------------------- readout (n2g is sorted)
__global__ __launch_bounds__(128) void k_readout(const __hip_bfloat16* __restrict__ h,
                                                 const float* __restrict__ h1,
                                                 const int* __restrict__ n2g,
                                                 float* __restrict__ feats) {
    const int CHN = 64;
    int d = threadIdx.x;
    int v0 = blockIdx.x * CHN;
    if (v0 >= NN) return;
    int v1 = v0 + CHN;
    if (v1 > NN) v1 = NN;
    float sum = 0.0f;
    int cur = n2g[v0];
    for (int v = v0; v < v1; ++v) {
        int gph = n2g[v];
        if (gph != cur) {
            atomicAdd(&feats[cur * DD + d], sum);
            sum = 0.0f;
            cur = gph;
        }
        sum += bf2f(h[(size_t)v * DD + d]) + h1[(size_t)v * DD + d];
    }
    atomicAdd(&feats[cur * DD + d], sum);
}

// ---------------------------------------------------------------- classifier
__global__ void k_cls(const float* __restrict__ feats, const float* __restrict__ Wc,
                      const float* __restrict__ bc, float* __restrict__ out) {
    int t = threadIdx.x;
    if (t >= BB * 2) return;
    int b = t >> 1, c = t & 1;
    float s = bc[c];
    for (int d = 0; d < DD; ++d) s += feats[b * DD + d] * Wc[d * 2 + c];
    out[t] = s;
}

// ================================================================ launcher
extern "C" void kernel_launch(void* const* d_in, const int* in_sizes, int n_in, void* d_out,
                              int out_size, void* d_ws, size_t ws_size, hipStream_t stream) {
    const float* features = (const float*)d_in[0];
    const int* src = (const int*)d_in[1];
    const int* dst = (const int*)d_in[2];
    const int* etype = (const int*)d_in[3];
    const int* n2g = (const int*)d_in[4];
    const float* W_msg = (const float*)d_in[5];
    const float* b_msg = (const float*)d_in[6];
    const float* w_ih = (const float*)d_in[7];
    const float* b_ih = (const float*)d_in[8];
    const float* w_hh = (const float*)d_in[9];
    const float* b_hh = (const float*)d_in[10];
    const float* W_cls = (const float*)d_in[11];
    const float* b_cls = (const float*)d_in[12];
    float* out = (float*)d_out;

    char* ws = (char*)d_ws;
    size_t o = 0;
    auto alloc = [&](size_t bytes) {
        o = (o + 255) & ~(size_t)255;
        void* p = ws + o;
        o += bytes;
        return p;
    };
    int* deg2 = (int*)alloc(sizeof(int) * NBIN);
    int* off2 = (int*)alloc(sizeof(int) * (NBIN + 1));
    int* cursor = (int*)alloc(sizeof(int) * NBIN);
    int* bsum = (int*)alloc(sizeof(int) * NBLK);
    int* boff = (int*)alloc(sizeof(int) * NBLK);
    int* csr_src = (int*)alloc(sizeof(int) * EE);
    __hip_bfloat16* W2f = (__hip_bfloat16*)alloc(sizeof(__hip_bfloat16) * W2F_N);
    float* Cmat = (float*)alloc(sizeof(float) * 4 * 384);
    float* bias512 = (float*)alloc(sizeof(float) * NGATES);
    float* hini = (float*)alloc(sizeof(float) * (size_t)NN * DD);
    __hip_bfloat16* hbfA = (__hip_bfloat16*)alloc(sizeof(__hip_bfloat16) * (size_t)NN * DD);
    __hip_bfloat16* hbfB = (__hip_bfloat16*)alloc(sizeof(__hip_bfloat16) * (size_t)NN * DD);
    __hip_bfloat16* g = (__hip_bfloat16*)alloc(sizeof(__hip_bfloat16) * (size_t)NN * KAGG);
    float* feats = (float*)alloc(sizeof(float) * BB * DD);

    // setup
    k_init_h<<<(NN * DD + 255) / 256, 256, 0, stream>>>(features, hini, hbfA);
    k_zero_i32<<<(NBIN + 255) / 256, 256, 0, stream>>>(deg2, NBIN);
    k_zero_f32<<<(BB * DD + 255) / 256, 256, 0, stream>>>(feats, BB * DD);
    k_hist<<<(EE + 255) / 256, 256, 0, stream>>>(dst, etype, deg2);
    k_scan_bsum<<<NBLK, 256, 0, stream>>>(deg2, bsum);
    k_scan_boff<<<1, 1024, 0, stream>>>(bsum, boff);
    k_scan_final<<<NBLK, 256, 0, stream>>>(deg2, boff, off2, cursor);
    k_fill<<<(EE + 255) / 256, 256, 0, stream>>>(dst, src, etype, cursor, csr_src);
    {
        int prep_n = W2F_N + 4 * 384 + NGATES;
        k_prep_w2f<<<(prep_n + 255) / 256, 256, 0, stream>>>(W_msg, b_msg, w_ih, w_hh,
                                                             b_ih, b_hh, W2f, Cmat, bias512);
    }

    __hip_bfloat16* hbc = hbfA;
    __hip_bfloat16* hbx = hbfB;
    for (int s = 0; s < STEPS; ++s) {
        k_agg<<<(NN * 64 + 255) / 256, 256, 0, stream>>>(hbc, off2, csr_src, g);
        k_step<<<MT64, 512, 0, stream>>>(g, W2f, Cmat, bias512, off2, hbc, hbx);
        __hip_bfloat16* tb = hbc; hbc = hbx; hbx = tb;
    }
    k_readout<<<(NN + 63) / 64, 128, 0, stream>>>(hbc, hini, n2g, feats);
    k_cls<<<1, 128, 0, stream>>>(feats, W_cls, b_cls, out);
}

// Round 14
// 750.222 us; speedup vs baseline: 1.0284x; 1.0284x over previous
//
#include <hip/hip_runtime.h>
#include <hip/hip_bf16.h>
#include <math.h>

// Problem constants (fixed by the reference)
#define NN 50000
#define EE 400000
#define TT 4
#define DIN 64
#define DD 128
#define BB 64
#define STEPS 8
#define KAGG 544    // 512 (T*D) + 4 (per-type counts for b_msg) + 28 pad -> 17*32
#define NGATES 512  // [r_sum, z_sum, i_n, h_n]
#define NBIN (4 * NN)             // (dst, etype) bins
#define NBLK ((NBIN + 255) / 256) // 782 scan blocks
#define MT64 ((NN + 63) / 64)     // 782 step blocks
#define W2F_N (21 * 12288)        // fragment-ordered W2: [kc][gb][wave][lane][8]

typedef __attribute__((ext_vector_type(8))) short bf16x8;
typedef __attribute__((ext_vector_type(4))) float f32x4;
typedef __attribute__((address_space(3))) void lds_void;
typedef __attribute__((address_space(1))) void glob_void;

__device__ inline float bf2f(__hip_bfloat16 x) { return __bfloat162float(x); }

// exact bf16(bit pattern in short) -> f32, value-based (vector elements have no address)
__device__ inline float s2f(short s) {
    unsigned int u = ((unsigned int)(unsigned short)s) << 16;
    float f;
    __builtin_memcpy(&f, &u, 4);
    return f;
}

// ---------------------------------------------------------------- init (zero-pad 64->128)
__global__ void k_init_h(const float* __restrict__ feat, float* __restrict__ h1,
                         __hip_bfloat16* __restrict__ hb) {
    int idx = blockIdx.x * blockDim.x + threadIdx.x;
    if (idx >= NN * DD) return;
    int v = idx >> 7, d = idx & 127;
    float val = (d < DIN) ? feat[v * DIN + d] : 0.0f;
    h1[idx] = val;
    hb[idx] = __float2bfloat16(val);
}

__global__ void k_zero_i32(int* __restrict__ p, int n) {
    int idx = blockIdx.x * blockDim.x + threadIdx.x;
    if (idx < n) p[idx] = 0;
}
__global__ void k_zero_f32(float* __restrict__ p, int n) {
    int idx = blockIdx.x * blockDim.x + threadIdx.x;
    if (idx < n) p[idx] = 0.0f;
}

// ---------------------------------------------------------------- CSR build by (dst,type)
__global__ void k_hist(const int* __restrict__ dst, const int* __restrict__ etype,
                       int* __restrict__ deg2) {
    int e = blockIdx.x * blockDim.x + threadIdx.x;
    if (e < EE) atomicAdd(&deg2[dst[e] * 4 + etype[e]], 1);
}

__global__ __launch_bounds__(256) void k_scan_bsum(const int* __restrict__ deg2,
                                                   int* __restrict__ bsum) {
    __shared__ int red[256];
    int tid = threadIdx.x;
    int i = blockIdx.x * 256 + tid;
    int v = (i < NBIN) ? deg2[i] : 0;
    red[tid] = v;
    __syncthreads();
#pragma unroll
    for (int s = 128; s > 0; s >>= 1) {
        if (tid < s) red[tid] += red[tid + s];
        __syncthreads();
    }
    if (tid == 0) bsum[blockIdx.x] = red[0];
}

__global__ __launch_bounds__(1024) void k_scan_boff(const int* __restrict__ bsum,
                                                    int* __restrict__ boff) {
    __shared__ int s[1024];
    int tid = threadIdx.x;
    int v = (tid < NBLK) ? bsum[tid] : 0;
    s[tid] = v;
    __syncthreads();
    for (int d = 1; d < 1024; d <<= 1) {
        int t = (tid >= d) ? s[tid - d] : 0;
        __syncthreads();
        s[tid] += t;
        __syncthreads();
    }
    if (tid < NBLK) boff[tid] = s[tid] - v;  // exclusive
}

__global__ __launch_bounds__(256) void k_scan_final(const int* __restrict__ deg2,
                                                    const int* __restrict__ boff,
                                                    int* __restrict__ off2,
                                                    int* __restrict__ cursor) {
    __shared__ int s[256];
    int tid = threadIdx.x;
    int i = blockIdx.x * 256 + tid;
    int v = (i < NBIN) ? deg2[i] : 0;
    s[tid] = v;
    __syncthreads();
#pragma unroll
    for (int d = 1; d < 256; d <<= 1) {
        int t = (tid >= d) ? s[tid - d] : 0;
        __syncthreads();
        s[tid] += t;
        __syncthreads();
    }
    int excl = boff[blockIdx.x] + s[tid] - v;
    if (i < NBIN) {
        off2[i] = excl;
        cursor[i] = excl;
        if (i == NBIN - 1) off2[NBIN] = excl + v;  // == EE
    }
}

__global__ void k_fill(const int* __restrict__ dst, const int* __restrict__ src,
                       const int* __restrict__ etype, int* __restrict__ cursor,
                       int* __restrict__ csr_src) {
    int e = blockIdx.x * blockDim.x + threadIdx.x;
    if (e < EE) {
        int pos = atomicAdd(&cursor[dst[e] * 4 + etype[e]], 1);
        csr_src[pos] = src[e];
    }
}

// counts columns of g (cols 512..515) constant across steps; zero pad 516..543.
__global__ void k_counts(const int* __restrict__ off2, __hip_bfloat16* __restrict__ g) {
    int idx = blockIdx.x * blockDim.x + threadIdx.x;
    if (idx >= NN * 16) return;
    int v = idx >> 4, j = idx & 15;
    float x = 0.0f, y = 0.0f;
    if (j < 2) {
        int t0 = 2 * j;
        x = (float)(off2[4 * v + t0 + 1] - off2[4 * v + t0]);
        y = (float)(off2[4 * v + t0 + 2] - off2[4 * v + t0 + 1]);
    }
    __hip_bfloat162 o;
    o.x = __float2bfloat16(x);
    o.y = __float2bfloat16(y);
    ((__hip_bfloat162*)(g + (size_t)v * KAGG))[256 + j] = o;
}

// ---------------------------------------------------------------- weight prep (once/call)
// Fragment-ordered composed weights W2f[kc 0..20][gb 0..2][wave 0..7][lane 0..63][8] bf16:
//   n(gate col) = {kc<17 or gb<2: gb*128, else 384(h_n)} + wave*16 + (lane&15)
//   k           = kc*32 + (lane>>4)*8 + j   (kc<17: g-part k 0..543; kc>=17: h-part)
// Per chunk kc this is ONE contiguous 24KB block; each wave's 3 B-fragments are
// contiguous 1KB slices -> direct global->register loads, no LDS needed for B.
__global__ void k_prep_w2f(const float* __restrict__ Wm, const float* __restrict__ bm,
                           const float* __restrict__ wih, const float* __restrict__ whh,
                           const float* __restrict__ bih, const float* __restrict__ bhh,
                           __hip_bfloat16* __restrict__ W2f, float* __restrict__ bias512) {
    int idx = blockIdx.x * blockDim.x + threadIdx.x;
    if (idx < W2F_N) {
        int kc = idx / 12288;
        int r1 = idx % 12288;
        int gb = r1 >> 12;
        int r2 = r1 & 4095;
        int w = r2 >> 9;
        int r3 = r2 & 511;
        int l = r3 >> 3;
        int j = r3 & 7;
        int npart = w * 16 + (l & 15);
        int kin = ((l >> 4) << 3) + j;
        float v = 0.0f;
        if (kc < 17) {
            int k = kc * 32 + kin;
            int n = gb * 128 + npart;  // 0..383: r, z, i_n
            if (k < 512) {
                int t = k >> 7, kd = k & 127;
                const float* wr = Wm + (t << 14) + (kd << 7);
                float s = 0.0f;
#pragma unroll 4
                for (int e = 0; e < 128; ++e) s += wr[e] * wih[e * 384 + n];
                v = s;
            } else if (k < 516) {
                const float* br = bm + ((k - 512) << 7);
                float s = 0.0f;
#pragma unroll 4
                for (int e = 0; e < 128; ++e) s += br[e] * wih[e * 384 + n];
                v = s;
            }
        } else {
            int kh = (kc - 17) * 32 + kin;  // 0..127
            int nlog = (gb < 2) ? gb * 128 + npart : 384 + npart;  // r,z,h_n
            int col = (nlog < 256) ? nlog : nlog - 128;            // w_hh col
            v = whh[kh * 384 + col];
        }
        W2f[idx] = __float2bfloat16(v);
        return;
    }
    int b = idx - W2F_N;
    if (b < NGATES) {
        float v;
        if (b < 256) v = bih[b] + bhh[b];
        else if (b < 384) v = bih[b];
        else v = bhh[b - 128];
        bias512[b] = v;
    }
}

// ---------------------------------------------------------------- per-type aggregation v3
// One WAVE per node; 4x 16-lane GROUPS walk the node's 4 type-lists CONCURRENTLY.
// Gather-chain collapse: lane sub loads csr_src[base+sub] (16 indices per instr),
// __shfl broadcasts index r to its group -> all h-row loads are address-independent
// and issue back-to-back (chain depth ~2 latencies instead of cnt).
__global__ __launch_bounds__(256) void k_agg(const __hip_bfloat16* __restrict__ hb,
                                             const int* __restrict__ off2,
                                             const int* __restrict__ csr_src,
                                             __hip_bfloat16* __restrict__ g) {
    const int node = (blockIdx.x * blockDim.x + threadIdx.x) >> 6;
    const int lane = threadIdx.x & 63;
    if (node >= NN) return;
    const int t = lane >> 4;      // group = etype
    const int sub = lane & 15;    // 8 dims per lane
    const int gbase = lane & 48;  // group's lane base for shfl
    const int p0 = off2[4 * node + t];
    const int p1 = off2[4 * node + t + 1];
    float a[8];
#pragma unroll
    for (int j = 0; j < 8; ++j) a[j] = 0.0f;
    for (int base = p0; base < p1; base += 16) {
        int cnt = p1 - base;
        if (cnt > 16) cnt = 16;
        int idxv = (sub < cnt) ? csr_src[base + sub] : 0;
        int r = 0;
        for (; r + 1 < cnt; r += 2) {
            int s0 = __shfl(idxv, gbase + r);
            int s1 = __shfl(idxv, gbase + r + 1);
            bf16x8 v0 = *(const bf16x8*)(hb + (size_t)s0 * DD + sub * 8);
            bf16x8 v1 = *(const bf16x8*)(hb + (size_t)s1 * DD + sub * 8);
#pragma unroll
            for (int j = 0; j < 8; ++j) a[j] += s2f(v0[j]) + s2f(v1[j]);
        }
        if (r < cnt) {
            int s0 = __shfl(idxv, gbase + r);
            bf16x8 v0 = *(const bf16x8*)(hb + (size_t)s0 * DD + sub * 8);
#pragma unroll
            for (int j = 0; j < 8; ++j) a[j] += s2f(v0[j]);
        }
    }
    bf16x8 o;
#pragma unroll
    for (int j = 0; j < 8; ++j) {
        __hip_bfloat16 b = __float2bfloat16(a[j]);
        o[j] = *(short*)&b;
    }
    *(bf16x8*)(g + (size_t)node * KAGG + t * 128 + sub * 8) = o;
}

// ---------------------------------------------------------------- fused step kernel (v7)
// (round-12 verified: 51.2 us) A through LDS (2-buffer ping-pong, global_load_lds
// + swizzle). B direct global->register from fragment-ordered W2f (no inter-wave
// B sharing -> no LDS). 21 chunks (17 g+counts, 4 h); bias-only epilogue.
__global__ __launch_bounds__(512, 4) void k_step(const __hip_bfloat16* __restrict__ g,
                                                 const __hip_bfloat16* __restrict__ W2f,
                                                 const float* __restrict__ bias512,
                                                 const __hip_bfloat16* __restrict__ hbi,
                                                 __hip_bfloat16* __restrict__ hbo) {
    __shared__ __align__(16) short As[2][64 * 32];  // 2 x 4 KB ping-pong
    __shared__ __align__(16) short Ht[64 * 132];    // 16.9 KB epilogue stage
    const int tid = threadIdx.x;
    const int lane = tid & 63;
    const int wave = tid >> 6;
    const int row0 = blockIdx.x * 64;
    const int quad = lane >> 4;
    const int m16 = lane & 15;
    const int koff = ((quad ^ ((m16 ^ (m16 >> 2)) & 3)) << 3);  // A swizzle (shorts)

    // A staging mapping (waves 0..3; slot = tid < 256)
    const int arow = tid >> 2;
    const int apart = (tid & 3) ^ ((arow ^ (arow >> 2)) & 3);
    int agrow = row0 + arow;
    if (agrow >= NN) agrow = NN - 1;
    const __hip_bfloat16* gA = g + (size_t)agrow * KAGG + apart * 8;
    const __hip_bfloat16* hA = hbi + (size_t)agrow * DD + apart * 8;
    const __hip_bfloat16* bw = W2f + ((size_t)(wave * 64 + lane)) * 8;  // own fragment base

    auto stage_A = [&](int kc) {
        if (wave < 4) {
            const glob_void* srcA = (kc < 17)
                                        ? (const glob_void*)(gA + kc * 32)
                                        : (const glob_void*)(hA + (kc - 17) * 32);
            __builtin_amdgcn_global_load_lds(srcA, (lds_void*)&As[kc & 1][(wave * 64) * 8],
                                             16, 0, 0);
        }
    };

    f32x4 acc[4][4];  // [row-tile][gate: r,z,in,hn]
#pragma unroll
    for (int rt = 0; rt < 4; ++rt)
#pragma unroll
        for (int c = 0; c < 4; ++c) acc[rt][c] = (f32x4){0.f, 0.f, 0.f, 0.f};

    stage_A(0);
    __syncthreads();

    for (int ki = 0; ki < 21; ++ki) {
        if (ki + 1 < 21) stage_A(ki + 1);

        // B: direct global->register, own contiguous 1KB fragments (L2-hot)
        const __hip_bfloat16* bp = bw + ki * 12288;
        bf16x8 b0 = *(const bf16x8*)(bp);
        bf16x8 b1 = *(const bf16x8*)(bp + 4096);
        bf16x8 b2 = *(const bf16x8*)(bp + 8192);

        bf16x8 af[4];
#pragma unroll
        for (int rt = 0; rt < 4; ++rt)
            af[rt] = *(const bf16x8*)&As[ki & 1][(rt * 16 + m16) * 32 + koff];
#pragma unroll
        for (int rt = 0; rt < 4; ++rt)
            acc[rt][0] = __builtin_amdgcn_mfma_f32_16x16x32_bf16(af[rt], b0, acc[rt][0], 0, 0, 0);
#pragma unroll
        for (int rt = 0; rt < 4; ++rt)
            acc[rt][1] = __builtin_amdgcn_mfma_f32_16x16x32_bf16(af[rt], b1, acc[rt][1], 0, 0, 0);
        if (ki < 17) {
#pragma unroll
            for (int rt = 0; rt < 4; ++rt)
                acc[rt][2] = __builtin_amdgcn_mfma_f32_16x16x32_bf16(af[rt], b2, acc[rt][2], 0, 0, 0);
        } else {
#pragma unroll
            for (int rt = 0; rt < 4; ++rt)
                acc[rt][3] = __builtin_amdgcn_mfma_f32_16x16x32_bf16(af[rt], b2, acc[rt][3], 0, 0, 0);
        }
        __syncthreads();  // drains stage_A(ki+1); As[ki&1] free for reuse next iter
    }

    // ---------------- epilogue: in-register GRU -> LDS (stride 132) -> full-line store
    {
        const int d = wave * 16 + m16;
        const float brs = bias512[d];
        const float bzs = bias512[128 + d];
        const float bin_ = bias512[256 + d];
        const float bhn = bias512[384 + d];
#pragma unroll
        for (int rt = 0; rt < 4; ++rt) {
#pragma unroll
            for (int j = 0; j < 4; ++j) {
                const int rowl = rt * 16 + quad * 4 + j;
                const int grow = row0 + rowl;
                const float rs = acc[rt][0][j] + brs;
                const float zs = acc[rt][1][j] + bzs;
                const float inn = acc[rt][2][j] + bin_;
                const float hnn = acc[rt][3][j] + bhn;
                const float rr = 1.0f / (1.0f + __expf(-rs));
                const float zz = 1.0f / (1.0f + __expf(-zs));
                const float ex = __expf(2.0f * (inn + rr * hnn));
                const float ng = 1.0f - 2.0f / (ex + 1.0f);  // tanh, overflow-safe
                const float hv =
                    bf2f(hbi[(size_t)(grow < NN ? grow : NN - 1) * DD + d]);
                const float o = (1.0f - zz) * ng + zz * hv;
                __hip_bfloat16 ob = __float2bfloat16(o);
                Ht[rowl * 132 + d] = *(short*)&ob;
            }
        }
    }
    __syncthreads();
    {
        // 512 threads x 32 B contiguous -> fully-coalesced full-line stores
        const int row = tid >> 3;
        const int col = (tid & 7) * 16;
        if (row0 + row < NN) {
            bf16x8 v0 = *(const bf16x8*)&Ht[row * 132 + col];
            bf16x8 v1 = *(const bf16x8*)&Ht[row * 132 + col + 8];
            __hip_bfloat16* dstp = hbo + (size_t)(row0 + row) * DD + col;
            *(bf16x8*)dstp = v0;
            *(bf16x8*)(dstp + 8) = v1;
        }
    }
}

// ---------------------------------------------------------------- readout (n2g is sorted)
__global__ __launch_bounds__(128) void k_readout(const __hip_bfloat16* __restrict__ h,
                                                 const float* __restrict__ h1,
                                                 const int* __restrict__ n2g,
                                                 float* __restrict__ feats) {
    const int CHN = 64;
    int d = threadIdx.x;
    int v0 = blockIdx.x * CHN;
    if (v0 >= NN) return;
    int v1 = v0 + CHN;
    if (v1 > NN) v1 = NN;
    float sum = 0.0f;
    int cur = n2g[v0];
    for (int v = v0; v < v1; ++v) {
        int gph = n2g[v];
        if (gph != cur) {
            atomicAdd(&feats[cur * DD + d], sum);
            sum = 0.0f;
            cur = gph;
        }
        sum += bf2f(h[(size_t)v * DD + d]) + h1[(size_t)v * DD + d];
    }
    atomicAdd(&feats[cur * DD + d], sum);
}

// ---------------------------------------------------------------- classifier
__global__ void k_cls(const float* __restrict__ feats, const float* __restrict__ Wc,
                      const float* __restrict__ bc, float* __restrict__ out) {
    int t = threadIdx.x;
    if (t >= BB * 2) return;
    int b = t >> 1, c = t & 1;
    float s = bc[c];
    for (int d = 0; d < DD; ++d) s += feats[b * DD + d] * Wc[d * 2 + c];
    out[t] = s;
}

// ================================================================ launcher
extern "C" void kernel_launch(void* const* d_in, const int* in_sizes, int n_in, void* d_out,
                              int out_size, void* d_ws, size_t ws_size, hipStream_t stream) {
    const float* features = (const float*)d_in[0];
    const int* src = (const int*)d_in[1];
    const int* dst = (const int*)d_in[2];
    const int* etype = (const int*)d_in[3];
    const int* n2g = (const int*)d_in[4];
    const float* W_msg = (const float*)d_in[5];
    const float* b_msg = (const float*)d_in[6];
    const float* w_ih = (const float*)d_in[7];
    const float* b_ih = (const float*)d_in[8];
    const float* w_hh = (const float*)d_in[9];
    const float* b_hh = (const float*)d_in[10];
    const float* W_cls = (const float*)d_in[11];
    const float* b_cls = (const float*)d_in[12];
    float* out = (float*)d_out;

    char* ws = (char*)d_ws;
    size_t o = 0;
    auto alloc = [&](size_t bytes) {
        o = (o + 255) & ~(size_t)255;
        void* p = ws + o;
        o += bytes;
        return p;
    };
    int* deg2 = (int*)alloc(sizeof(int) * NBIN);
    int* off2 = (int*)alloc(sizeof(int) * (NBIN + 1));
    int* cursor = (int*)alloc(sizeof(int) * NBIN);
    int* bsum = (int*)alloc(sizeof(int) * NBLK);
    int* boff = (int*)alloc(sizeof(int) * NBLK);
    int* csr_src = (int*)alloc(sizeof(int) * EE);
    __hip_bfloat16* W2f = (__hip_bfloat16*)alloc(sizeof(__hip_bfloat16) * W2F_N);
    float* bias512 = (float*)alloc(sizeof(float) * NGATES);
    float* hini = (float*)alloc(sizeof(float) * (size_t)NN * DD);
    __hip_bfloat16* hbfA = (__hip_bfloat16*)alloc(sizeof(__hip_bfloat16) * (size_t)NN * DD);
    __hip_bfloat16* hbfB = (__hip_bfloat16*)alloc(sizeof(__hip_bfloat16) * (size_t)NN * DD);
    __hip_bfloat16* g = (__hip_bfloat16*)alloc(sizeof(__hip_bfloat16) * (size_t)NN * KAGG);
    float* feats = (float*)alloc(sizeof(float) * BB * DD);

    // setup
    k_init_h<<<(NN * DD + 255) / 256, 256, 0, stream>>>(features, hini, hbfA);
    k_zero_i32<<<(NBIN + 255) / 256, 256, 0, stream>>>(deg2, NBIN);
    k_zero_f32<<<(BB * DD + 255) / 256, 256, 0, stream>>>(feats, BB * DD);
    k_hist<<<(EE + 255) / 256, 256, 0, stream>>>(dst, etype, deg2);
    k_scan_bsum<<<NBLK, 256, 0, stream>>>(deg2, bsum);
    k_scan_boff<<<1, 1024, 0, stream>>>(bsum, boff);
    k_scan_final<<<NBLK, 256, 0, stream>>>(deg2, boff, off2, cursor);
    k_fill<<<(EE + 255) / 256, 256, 0, stream>>>(dst, src, etype, cursor, csr_src);
    k_counts<<<(NN * 16 + 255) / 256, 256, 0, stream>>>(off2, g);
    {
        int prep_n = W2F_N + NGATES;
        k_prep_w2f<<<(prep_n + 255) / 256, 256, 0, stream>>>(W_msg, b_msg, w_ih, w_hh,
                                                             b_ih, b_hh, W2f, bias512);
    }

    __hip_bfloat16* hbc = hbfA;
    __hip_bfloat16* hbx = hbfB;
    for (int s = 0; s < STEPS; ++s) {
        k_agg<<<(NN * 64 + 255) / 256, 256, 0, stream>>>(hbc, off2, csr_src, g);
        k_step<<<MT64, 512, 0, stream>>>(g, W2f, bias512, hbc, hbx);
        __hip_bfloat16* tb = hbc; hbc = hbx; hbx = tb;
    }
    k_readout<<<(NN + 63) / 64, 128, 0, stream>>>(hbc, hini, n2g, feats);
    k_cls<<<1, 128, 0, stream>>>(feats, W_cls, b_cls, out);
}

// Round 15
// 726.582 us; speedup vs baseline: 1.0619x; 1.0325x over previous
//
#include <hip/hip_runtime.h>
#include <hip/hip_bf16.h>
#include <math.h>

// Problem constants (fixed by the reference)
#define NN 50000
#define EE 400000
#define TT 4
#define DIN 64
#define DD 128
#define BB 64
#define STEPS 8
#define KAGG 544    // 512 (T*D) + 4 (per-type counts for b_msg) + 28 pad -> 17*32
#define NGATES 512  // [r_sum, z_sum, i_n, h_n]
#define NBIN (4 * NN)             // (dst, etype) bins
#define NBLK ((NBIN + 255) / 256) // 782 scan blocks
#define MT64 ((NN + 63) / 64)     // 782 step blocks
#define W2F_N (21 * 12288)        // fragment-ordered W2: [kc][gb][wave][lane][8]

typedef __attribute__((ext_vector_type(8))) short bf16x8;
typedef __attribute__((ext_vector_type(4))) float f32x4;
typedef __attribute__((address_space(3))) void lds_void;
typedef __attribute__((address_space(1))) void glob_void;

__device__ inline float bf2f(__hip_bfloat16 x) { return __bfloat162float(x); }

// exact bf16(bit pattern in short) -> f32, value-based (vector elements have no address)
__device__ inline float s2f(short s) {
    unsigned int u = ((unsigned int)(unsigned short)s) << 16;
    float f;
    __builtin_memcpy(&f, &u, 4);
    return f;
}

// ---------------------------------------------------------------- init (zero-pad 64->128)
__global__ void k_init_h(const float* __restrict__ feat, float* __restrict__ h1,
                         __hip_bfloat16* __restrict__ hb) {
    int idx = blockIdx.x * blockDim.x + threadIdx.x;
    if (idx >= NN * DD) return;
    int v = idx >> 7, d = idx & 127;
    float val = (d < DIN) ? feat[v * DIN + d] : 0.0f;
    h1[idx] = val;
    hb[idx] = __float2bfloat16(val);
}

// one launch zeroes both deg2 and feats
__global__ void k_zero2(int* __restrict__ deg2, float* __restrict__ feats) {
    int idx = blockIdx.x * blockDim.x + threadIdx.x;
    if (idx < NBIN) deg2[idx] = 0;
    else if (idx < NBIN + BB * DD) feats[idx - NBIN] = 0.0f;
}

// ---------------------------------------------------------------- CSR build by (dst,type)
__global__ void k_hist(const int* __restrict__ dst, const int* __restrict__ etype,
                       int* __restrict__ deg2) {
    int e = blockIdx.x * blockDim.x + threadIdx.x;
    if (e < EE) atomicAdd(&deg2[dst[e] * 4 + etype[e]], 1);
}

__global__ __launch_bounds__(256) void k_scan_bsum(const int* __restrict__ deg2,
                                                   int* __restrict__ bsum) {
    __shared__ int red[256];
    int tid = threadIdx.x;
    int i = blockIdx.x * 256 + tid;
    int v = (i < NBIN) ? deg2[i] : 0;
    red[tid] = v;
    __syncthreads();
#pragma unroll
    for (int s = 128; s > 0; s >>= 1) {
        if (tid < s) red[tid] += red[tid + s];
        __syncthreads();
    }
    if (tid == 0) bsum[blockIdx.x] = red[0];
}

__global__ __launch_bounds__(1024) void k_scan_boff(const int* __restrict__ bsum,
                                                    int* __restrict__ boff) {
    __shared__ int s[1024];
    int tid = threadIdx.x;
    int v = (tid < NBLK) ? bsum[tid] : 0;
    s[tid] = v;
    __syncthreads();
    for (int d = 1; d < 1024; d <<= 1) {
        int t = (tid >= d) ? s[tid - d] : 0;
        __syncthreads();
        s[tid] += t;
        __syncthreads();
    }
    if (tid < NBLK) boff[tid] = s[tid] - v;  // exclusive
}

// scan_final also writes g's count columns (cols 512..515 = deg2 value, already in
// a register here) and zeroes the pad cols 516..543 -- replaces the k_counts launch.
__global__ __launch_bounds__(256) void k_scan_final(const int* __restrict__ deg2,
                                                    const int* __restrict__ boff,
                                                    int* __restrict__ off2,
                                                    int* __restrict__ cursor,
                                                    __hip_bfloat16* __restrict__ g) {
    __shared__ int s[256];
    int tid = threadIdx.x;
    int i = blockIdx.x * 256 + tid;
    int v = (i < NBIN) ? deg2[i] : 0;
    s[tid] = v;
    __syncthreads();
#pragma unroll
    for (int d = 1; d < 256; d <<= 1) {
        int t = (tid >= d) ? s[tid - d] : 0;
        __syncthreads();
        s[tid] += t;
        __syncthreads();
    }
    int excl = boff[blockIdx.x] + s[tid] - v;
    if (i < NBIN) {
        off2[i] = excl;
        cursor[i] = excl;
        if (i == NBIN - 1) off2[NBIN] = excl + v;  // == EE
        // counts + pad columns of g (constant across steps)
        int node = i >> 2, t = i & 3;
        __hip_bfloat16* grow = g + (size_t)node * KAGG + 512;
        grow[t] = __float2bfloat16((float)v);
        __hip_bfloat16 z = __float2bfloat16(0.0f);
#pragma unroll
        for (int p = 0; p < 7; ++p) grow[4 + t * 7 + p] = z;  // cols 516..543
    }
}

__global__ void k_fill(const int* __restrict__ dst, const int* __restrict__ src,
                       const int* __restrict__ etype, int* __restrict__ cursor,
                       int* __restrict__ csr_src) {
    int e = blockIdx.x * blockDim.x + threadIdx.x;
    if (e < EE) {
        int pos = atomicAdd(&cursor[dst[e] * 4 + etype[e]], 1);
        csr_src[pos] = src[e];
    }
}

// ---------------------------------------------------------------- weight prep (once/call)
// Fragment-ordered composed weights W2f[kc 0..20][gb 0..2][wave 0..7][lane 0..63][8] bf16:
//   n(gate col) = {kc<17 or gb<2: gb*128, else 384(h_n)} + wave*16 + (lane&15)
//   k           = kc*32 + (lane>>4)*8 + j   (kc<17: g-part k 0..543; kc>=17: h-part)
// Per chunk kc this is ONE contiguous 24KB block; each wave's 3 B-fragments are
// contiguous 1KB slices -> direct global->register loads, no LDS needed for B.
__global__ void k_prep_w2f(const float* __restrict__ Wm, const float* __restrict__ bm,
                           const float* __restrict__ wih, const float* __restrict__ whh,
                           const float* __restrict__ bih, const float* __restrict__ bhh,
                           __hip_bfloat16* __restrict__ W2f, float* __restrict__ bias512) {
    int idx = blockIdx.x * blockDim.x + threadIdx.x;
    if (idx < W2F_N) {
        int kc = idx / 12288;
        int r1 = idx % 12288;
        int gb = r1 >> 12;
        int r2 = r1 & 4095;
        int w = r2 >> 9;
        int r3 = r2 & 511;
        int l = r3 >> 3;
        int j = r3 & 7;
        int npart = w * 16 + (l & 15);
        int kin = ((l >> 4) << 3) + j;
        float v = 0.0f;
        if (kc < 17) {
            int k = kc * 32 + kin;
            int n = gb * 128 + npart;  // 0..383: r, z, i_n
            if (k < 512) {
                int t = k >> 7, kd = k & 127;
                const float* wr = Wm + (t << 14) + (kd << 7);
                float s = 0.0f;
#pragma unroll 4
                for (int e = 0; e < 128; ++e) s += wr[e] * wih[e * 384 + n];
                v = s;
            } else if (k < 516) {
                const float* br = bm + ((k - 512) << 7);
                float s = 0.0f;
#pragma unroll 4
                for (int e = 0; e < 128; ++e) s += br[e] * wih[e * 384 + n];
                v = s;
            }
        } else {
            int kh = (kc - 17) * 32 + kin;  // 0..127
            int nlog = (gb < 2) ? gb * 128 + npart : 384 + npart;  // r,z,h_n
            int col = (nlog < 256) ? nlog : nlog - 128;            // w_hh col
            v = whh[kh * 384 + col];
        }
        W2f[idx] = __float2bfloat16(v);
        return;
    }
    int b = idx - W2F_N;
    if (b < NGATES) {
        float v;
        if (b < 256) v = bih[b] + bhh[b];
        else if (b < 384) v = bih[b];
        else v = bhh[b - 128];
        bias512[b] = v;
    }
}

// ---------------------------------------------------------------- per-type aggregation v3
// One WAVE per node; 4x 16-lane GROUPS walk the node's 4 type-lists CONCURRENTLY.
// Gather-chain collapse: lane sub loads csr_src[base+sub] (16 indices per instr),
// __shfl broadcasts index r to its group -> all h-row loads are address-independent
// and issue back-to-back (chain depth ~2 latencies instead of cnt).
__global__ __launch_bounds__(256) void k_agg(const __hip_bfloat16* __restrict__ hb,
                                             const int* __restrict__ off2,
                                             const int* __restrict__ csr_src,
                                             __hip_bfloat16* __restrict__ g) {
    const int node = (blockIdx.x * blockDim.x + threadIdx.x) >> 6;
    const int lane = threadIdx.x & 63;
    if (node >= NN) return;
    const int t = lane >> 4;      // group = etype
    const int sub = lane & 15;    // 8 dims per lane
    const int gbase = lane & 48;  // group's lane base for shfl
    const int p0 = off2[4 * node + t];
    const int p1 = off2[4 * node + t + 1];
    float a[8];
#pragma unroll
    for (int j = 0; j < 8; ++j) a[j] = 0.0f;
    for (int base = p0; base < p1; base += 16) {
        int cnt = p1 - base;
        if (cnt > 16) cnt = 16;
        int idxv = (sub < cnt) ? csr_src[base + sub] : 0;
        int r = 0;
        for (; r + 1 < cnt; r += 2) {
            int s0 = __shfl(idxv, gbase + r);
            int s1 = __shfl(idxv, gbase + r + 1);
            bf16x8 v0 = *(const bf16x8*)(hb + (size_t)s0 * DD + sub * 8);
            bf16x8 v1 = *(const bf16x8*)(hb + (size_t)s1 * DD + sub * 8);
#pragma unroll
            for (int j = 0; j < 8; ++j) a[j] += s2f(v0[j]) + s2f(v1[j]);
        }
        if (r < cnt) {
            int s0 = __shfl(idxv, gbase + r);
            bf16x8 v0 = *(const bf16x8*)(hb + (size_t)s0 * DD + sub * 8);
#pragma unroll
            for (int j = 0; j < 8; ++j) a[j] += s2f(v0[j]);
        }
    }
    bf16x8 o;
#pragma unroll
    for (int j = 0; j < 8; ++j) {
        __hip_bfloat16 b = __float2bfloat16(a[j]);
        o[j] = *(short*)&b;
    }
    *(bf16x8*)(g + (size_t)node * KAGG + t * 128 + sub * 8) = o;
}

// ---------------------------------------------------------------- fused step kernel (v7b)
// (round-12/14 verified structure: ~52 us) A through LDS (2-buffer ping-pong,
// global_load_lds + swizzle). B direct global->register from fragment-ordered W2f.
// This round: B loads issued FIRST after the barrier (longest-latency op heads the
// critical path), then stage_A issue, then af ds_reads.
__global__ __launch_bounds__(512, 4) void k_step(const __hip_bfloat16* __restrict__ g,
                                                 const __hip_bfloat16* __restrict__ W2f,
                                                 const float* __restrict__ bias512,
                                                 const __hip_bfloat16* __restrict__ hbi,
                                                 __hip_bfloat16* __restrict__ hbo) {
    __shared__ __align__(16) short As[2][64 * 32];  // 2 x 4 KB ping-pong
    __shared__ __align__(16) short Ht[64 * 132];    // 16.9 KB epilogue stage
    const int tid = threadIdx.x;
    const int lane = tid & 63;
    const int wave = tid >> 6;
    const int row0 = blockIdx.x * 64;
    const int quad = lane >> 4;
    const int m16 = lane & 15;
    const int koff = ((quad ^ ((m16 ^ (m16 >> 2)) & 3)) << 3);  // A swizzle (shorts)

    // A staging mapping (waves 0..3; slot = tid < 256)
    const int arow = tid >> 2;
    const int apart = (tid & 3) ^ ((arow ^ (arow >> 2)) & 3);
    int agrow = row0 + arow;
    if (agrow >= NN) agrow = NN - 1;
    const __hip_bfloat16* gA = g + (size_t)agrow * KAGG + apart * 8;
    const __hip_bfloat16* hA = hbi + (size_t)agrow * DD + apart * 8;
    const __hip_bfloat16* bw = W2f + ((size_t)(wave * 64 + lane)) * 8;  // own fragment base

    auto stage_A = [&](int kc) {
        if (wave < 4) {
            const glob_void* srcA = (kc < 17)
                                        ? (const glob_void*)(gA + kc * 32)
                                        : (const glob_void*)(hA + (kc - 17) * 32);
            __builtin_amdgcn_global_load_lds(srcA, (lds_void*)&As[kc & 1][(wave * 64) * 8],
                                             16, 0, 0);
        }
    };

    f32x4 acc[4][4];  // [row-tile][gate: r,z,in,hn]
#pragma unroll
    for (int rt = 0; rt < 4; ++rt)
#pragma unroll
        for (int c = 0; c < 4; ++c) acc[rt][c] = (f32x4){0.f, 0.f, 0.f, 0.f};

    stage_A(0);
    __syncthreads();

    for (int ki = 0; ki < 21; ++ki) {
        // B first: direct global->register, own contiguous 1KB fragments (L2-hot).
        // Issued at the head of the chunk so its L2 latency overlaps stage_A issue
        // and the af ds_reads below.
        const __hip_bfloat16* bp = bw + ki * 12288;
        bf16x8 b0 = *(const bf16x8*)(bp);
        bf16x8 b1 = *(const bf16x8*)(bp + 4096);
        bf16x8 b2 = *(const bf16x8*)(bp + 8192);

        if (ki + 1 < 21) stage_A(ki + 1);

        bf16x8 af[4];
#pragma unroll
        for (int rt = 0; rt < 4; ++rt)
            af[rt] = *(const bf16x8*)&As[ki & 1][(rt * 16 + m16) * 32 + koff];
#pragma unroll
        for (int rt = 0; rt < 4; ++rt)
            acc[rt][0] = __builtin_amdgcn_mfma_f32_16x16x32_bf16(af[rt], b0, acc[rt][0], 0, 0, 0);
#pragma unroll
        for (int rt = 0; rt < 4; ++rt)
            acc[rt][1] = __builtin_amdgcn_mfma_f32_16x16x32_bf16(af[rt], b1, acc[rt][1], 0, 0, 0);
        if (ki < 17) {
#pragma unroll
            for (int rt = 0; rt < 4; ++rt)
                acc[rt][2] = __builtin_amdgcn_mfma_f32_16x16x32_bf16(af[rt], b2, acc[rt][2], 0, 0, 0);
        } else {
#pragma unroll
            for (int rt = 0; rt < 4; ++rt)
                acc[rt][3] = __builtin_amdgcn_mfma_f32_16x16x32_bf16(af[rt], b2, acc[rt][3], 0, 0, 0);
        }
        __syncthreads();  // drains stage_A(ki+1); As[ki&1] free for reuse next iter
    }

    // ---------------- epilogue: in-register GRU -> LDS (stride 132) -> full-line store
    {
        const int d = wave * 16 + m16;
        const float brs = bias512[d];
        const float bzs = bias512[128 + d];
        const float bin_ = bias512[256 + d];
        const float bhn = bias512[384 + d];
#pragma unroll
        for (int rt = 0; rt < 4; ++rt) {
#pragma unroll
            for (int j = 0; j < 4; ++j) {
                const int rowl = rt * 16 + quad * 4 + j;
                const int grow = row0 + rowl;
                const float rs = acc[rt][0][j] + brs;
                const float zs = acc[rt][1][j] + bzs;
                const float inn = acc[rt][2][j] + bin_;
                const float hnn = acc[rt][3][j] + bhn;
                const float rr = 1.0f / (1.0f + __expf(-rs));
                const float zz = 1.0f / (1.0f + __expf(-zs));
                const float ex = __expf(2.0f * (inn + rr * hnn));
                const float ng = 1.0f - 2.0f / (ex + 1.0f);  // tanh, overflow-safe
                const float hv =
                    bf2f(hbi[(size_t)(grow < NN ? grow : NN - 1) * DD + d]);
                const float o = (1.0f - zz) * ng + zz * hv;
                __hip_bfloat16 ob = __float2bfloat16(o);
                Ht[rowl * 132 + d] = *(short*)&ob;
            }
        }
    }
    __syncthreads();
    {
        // 512 threads x 32 B contiguous -> fully-coalesced full-line stores
        const int row = tid >> 3;
        const int col = (tid & 7) * 16;
        if (row0 + row < NN) {
            bf16x8 v0 = *(const bf16x8*)&Ht[row * 132 + col];
            bf16x8 v1 = *(const bf16x8*)&Ht[row * 132 + col + 8];
            __hip_bfloat16* dstp = hbo + (size_t)(row0 + row) * DD + col;
            *(bf16x8*)dstp = v0;
            *(bf16x8*)(dstp + 8) = v1;
        }
    }
}

// ---------------------------------------------------------------- readout (n2g is sorted)
__global__ __launch_bounds__(128) void k_readout(const __hip_bfloat16* __restrict__ h,
                                                 const float* __restrict__ h1,
                                                 const int* __restrict__ n2g,
                                                 float* __restrict__ feats) {
    const int CHN = 64;
    int d = threadIdx.x;
    int v0 = blockIdx.x * CHN;
    if (v0 >= NN) return;
    int v1 = v0 + CHN;
    if (v1 > NN) v1 = NN;
    float sum = 0.0f;
    int cur = n2g[v0];
    for (int v = v0; v < v1; ++v) {
        int gph = n2g[v];
        if (gph != cur) {
            atomicAdd(&feats[cur * DD + d], sum);
            sum = 0.0f;
            cur = gph;
        }
        sum += bf2f(h[(size_t)v * DD + d]) + h1[(size_t)v * DD + d];
    }
    atomicAdd(&feats[cur * DD + d], sum);
}

// ---------------------------------------------------------------- classifier
__global__ void k_cls(const float* __restrict__ feats, const float* __restrict__ Wc,
                      const float* __restrict__ bc, float* __restrict__ out) {
    int t = threadIdx.x;
    if (t >= BB * 2) return;
    int b = t >> 1, c = t & 1;
    float s = bc[c];
    for (int d = 0; d < DD; ++d) s += feats[b * DD + d] * Wc[d * 2 + c];
    out[t] = s;
}

// ================================================================ launcher
extern "C" void kernel_launch(void* const* d_in, const int* in_sizes, int n_in, void* d_out,
                              int out_size, void* d_ws, size_t ws_size, hipStream_t stream) {
    const float* features = (const float*)d_in[0];
    const int* src = (const int*)d_in[1];
    const int* dst = (const int*)d_in[2];
    const int* etype = (const int*)d_in[3];
    const int* n2g = (const int*)d_in[4];
    const float* W_msg = (const float*)d_in[5];
    const float* b_msg = (const float*)d_in[6];
    const float* w_ih = (const float*)d_in[7];
    const float* b_ih = (const float*)d_in[8];
    const float* w_hh = (const float*)d_in[9];
    const float* b_hh = (const float*)d_in[10];
    const float* W_cls = (const float*)d_in[11];
    const float* b_cls = (const float*)d_in[12];
    float* out = (float*)d_out;

    char* ws = (char*)d_ws;
    size_t o = 0;
    auto alloc = [&](size_t bytes) {
        o = (o + 255) & ~(size_t)255;
        void* p = ws + o;
        o += bytes;
        return p;
    };
    int* deg2 = (int*)alloc(sizeof(int) * NBIN);
    int* off2 = (int*)alloc(sizeof(int) * (NBIN + 1));
    int* cursor = (int*)alloc(sizeof(int) * NBIN);
    int* bsum = (int*)alloc(sizeof(int) * NBLK);
    int* boff = (int*)alloc(sizeof(int) * NBLK);
    int* csr_src = (int*)alloc(sizeof(int) * EE);
    __hip_bfloat16* W2f = (__hip_bfloat16*)alloc(sizeof(__hip_bfloat16) * W2F_N);
    float* bias512 = (float*)alloc(sizeof(float) * NGATES);
    float* hini = (float*)alloc(sizeof(float) * (size_t)NN * DD);
    __hip_bfloat16* hbfA = (__hip_bfloat16*)alloc(sizeof(__hip_bfloat16) * (size_t)NN * DD);
    __hip_bfloat16* hbfB = (__hip_bfloat16*)alloc(sizeof(__hip_bfloat16) * (size_t)NN * DD);
    __hip_bfloat16* g = (__hip_bfloat16*)alloc(sizeof(__hip_bfloat16) * (size_t)NN * KAGG);
    float* feats = (float*)alloc(sizeof(float) * BB * DD);

    // setup
    k_init_h<<<(NN * DD + 255) / 256, 256, 0, stream>>>(features, hini, hbfA);
    k_zero2<<<(NBIN + BB * DD + 255) / 256, 256, 0, stream>>>(deg2, feats);
    k_hist<<<(EE + 255) / 256, 256, 0, stream>>>(dst, etype, deg2);
    k_scan_bsum<<<NBLK, 256, 0, stream>>>(deg2, bsum);
    k_scan_boff<<<1, 1024, 0, stream>>>(bsum, boff);
    k_scan_final<<<NBLK, 256, 0, stream>>>(deg2, boff, off2, cursor, g);
    k_fill<<<(EE + 255) / 256, 256, 0, stream>>>(dst, src, etype, cursor, csr_src);
    {
        int prep_n = W2F_N + NGATES;
        k_prep_w2f<<<(prep_n + 255) / 256, 256, 0, stream>>>(W_msg, b_msg, w_ih, w_hh,
                                                             b_ih, b_hh, W2f, bias512);
    }

    __hip_bfloat16* hbc = hbfA;
    __hip_bfloat16* hbx = hbfB;
    for (int s = 0; s < STEPS; ++s) {
        k_agg<<<(NN * 64 + 255) / 256, 256, 0, stream>>>(hbc, off2, csr_src, g);
        k_step<<<MT64, 512, 0, stream>>>(g, W2f, bias512, hbc, hbx);
        __hip_bfloat16* tb = hbc; hbc = hbx; hbx = tb;
    }
    k_readout<<<(NN + 63) / 64, 128, 0, stream>>>(hbc, hini, n2g, feats);
    k_cls<<<1, 128, 0, stream>>>(feats, W_cls, b_cls, out);
}

// Round 16
// 713.365 us; speedup vs baseline: 1.0816x; 1.0185x over previous
//
#include <hip/hip_runtime.h>
#include <hip/hip_bf16.h>
#include <math.h>

// Problem constants (fixed by the reference)
#define NN 50000
#define EE 400000
#define TT 4
#define DIN 64
#define DD 128
#define BB 64
#define STEPS 8
#define KAGG 544    // 512 (T*D) + 4 (per-type counts for b_msg) + 28 pad -> 17*32
#define NGATES 512  // [r_sum, z_sum, i_n, h_n]
#define NBIN (4 * NN)             // (dst, etype) bins
#define NBLK ((NBIN + 255) / 256) // 782 scan blocks
#define MT64 ((NN + 63) / 64)     // 782 step blocks
#define W2F_N (21 * 12288)        // fragment-ordered W2: [kc][gb][wave][lane][8]

typedef __attribute__((ext_vector_type(8))) short bf16x8;
typedef __attribute__((ext_vector_type(4))) float f32x4;
typedef __attribute__((address_space(3))) void lds_void;
typedef __attribute__((address_space(1))) void glob_void;

__device__ inline float bf2f(__hip_bfloat16 x) { return __bfloat162float(x); }

// exact bf16(bit pattern in short) -> f32, value-based (vector elements have no address)
__device__ inline float s2f(short s) {
    unsigned int u = ((unsigned int)(unsigned short)s) << 16;
    float f;
    __builtin_memcpy(&f, &u, 4);
    return f;
}

// ---------------------------------------------------------------- init (zero-pad 64->128)
__global__ void k_init_h(const float* __restrict__ feat, float* __restrict__ h1,
                         __hip_bfloat16* __restrict__ hb) {
    int idx = blockIdx.x * blockDim.x + threadIdx.x;
    if (idx >= NN * DD) return;
    int v = idx >> 7, d = idx & 127;
    float val = (d < DIN) ? feat[v * DIN + d] : 0.0f;
    h1[idx] = val;
    hb[idx] = __float2bfloat16(val);
}

// one launch zeroes both deg2 and feats
__global__ void k_zero2(int* __restrict__ deg2, float* __restrict__ feats) {
    int idx = blockIdx.x * blockDim.x + threadIdx.x;
    if (idx < NBIN) deg2[idx] = 0;
    else if (idx < NBIN + BB * DD) feats[idx - NBIN] = 0.0f;
}

// ---------------------------------------------------------------- CSR build by (dst,type)
__global__ void k_hist(const int* __restrict__ dst, const int* __restrict__ etype,
                       int* __restrict__ deg2) {
    int e = blockIdx.x * blockDim.x + threadIdx.x;
    if (e < EE) atomicAdd(&deg2[dst[e] * 4 + etype[e]], 1);
}

__global__ __launch_bounds__(256) void k_scan_bsum(const int* __restrict__ deg2,
                                                   int* __restrict__ bsum) {
    __shared__ int red[256];
    int tid = threadIdx.x;
    int i = blockIdx.x * 256 + tid;
    int v = (i < NBIN) ? deg2[i] : 0;
    red[tid] = v;
    __syncthreads();
#pragma unroll
    for (int s = 128; s > 0; s >>= 1) {
        if (tid < s) red[tid] += red[tid + s];
        __syncthreads();
    }
    if (tid == 0) bsum[blockIdx.x] = red[0];
}

__global__ __launch_bounds__(1024) void k_scan_boff(const int* __restrict__ bsum,
                                                    int* __restrict__ boff) {
    __shared__ int s[1024];
    int tid = threadIdx.x;
    int v = (tid < NBLK) ? bsum[tid] : 0;
    s[tid] = v;
    __syncthreads();
    for (int d = 1; d < 1024; d <<= 1) {
        int t = (tid >= d) ? s[tid - d] : 0;
        __syncthreads();
        s[tid] += t;
        __syncthreads();
    }
    if (tid < NBLK) boff[tid] = s[tid] - v;  // exclusive
}

// scan_final also writes g's count columns (cols 512..515 = deg2 value, already in
// a register here) and zeroes the pad cols 516..543 -- replaces the k_counts launch.
__global__ __launch_bounds__(256) void k_scan_final(const int* __restrict__ deg2,
                                                    const int* __restrict__ boff,
                                                    int* __restrict__ off2,
                                                    int* __restrict__ cursor,
                                                    __hip_bfloat16* __restrict__ g) {
    __shared__ int s[256];
    int tid = threadIdx.x;
    int i = blockIdx.x * 256 + tid;
    int v = (i < NBIN) ? deg2[i] : 0;
    s[tid] = v;
    __syncthreads();
#pragma unroll
    for (int d = 1; d < 256; d <<= 1) {
        int t = (tid >= d) ? s[tid - d] : 0;
        __syncthreads();
        s[tid] += t;
        __syncthreads();
    }
    int excl = boff[blockIdx.x] + s[tid] - v;
    if (i < NBIN) {
        off2[i] = excl;
        cursor[i] = excl;
        if (i == NBIN - 1) off2[NBIN] = excl + v;  // == EE
        // counts + pad columns of g (constant across steps)
        int node = i >> 2, t = i & 3;
        __hip_bfloat16* grow = g + (size_t)node * KAGG + 512;
        grow[t] = __float2bfloat16((float)v);
        __hip_bfloat16 z = __float2bfloat16(0.0f);
#pragma unroll
        for (int p = 0; p < 7; ++p) grow[4 + t * 7 + p] = z;  // cols 516..543
    }
}

__global__ void k_fill(const int* __restrict__ dst, const int* __restrict__ src,
                       const int* __restrict__ etype, int* __restrict__ cursor,
                       int* __restrict__ csr_src) {
    int e = blockIdx.x * blockDim.x + threadIdx.x;
    if (e < EE) {
        int pos = atomicAdd(&cursor[dst[e] * 4 + etype[e]], 1);
        csr_src[pos] = src[e];
    }
}

// ---------------------------------------------------------------- weight prep (once/call)
// Fragment-ordered composed weights W2f[kc 0..20][gb 0..2][wave 0..7][lane 0..63][8] bf16:
//   n(gate col) = {kc<17 or gb<2: gb*128, else 384(h_n)} + wave*16 + (lane&15)
//   k           = kc*32 + (lane>>4)*8 + j   (kc<17: g-part k 0..543; kc>=17: h-part)
// Per chunk kc this is ONE contiguous 24KB block; each wave's 3 B-fragments are
// contiguous 1KB slices -> direct global->register loads, no LDS needed for B.
__global__ void k_prep_w2f(const float* __restrict__ Wm, const float* __restrict__ bm,
                           const float* __restrict__ wih, const float* __restrict__ whh,
                           const float* __restrict__ bih, const float* __restrict__ bhh,
                           __hip_bfloat16* __restrict__ W2f, float* __restrict__ bias512) {
    int idx = blockIdx.x * blockDim.x + threadIdx.x;
    if (idx < W2F_N) {
        int kc = idx / 12288;
        int r1 = idx % 12288;
        int gb = r1 >> 12;
        int r2 = r1 & 4095;
        int w = r2 >> 9;
        int r3 = r2 & 511;
        int l = r3 >> 3;
        int j = r3 & 7;
        int npart = w * 16 + (l & 15);
        int kin = ((l >> 4) << 3) + j;
        float v = 0.0f;
        if (kc < 17) {
            int k = kc * 32 + kin;
            int n = gb * 128 + npart;  // 0..383: r, z, i_n
            if (k < 512) {
                int t = k >> 7, kd = k & 127;
                const float* wr = Wm + (t << 14) + (kd << 7);
                float s = 0.0f;
#pragma unroll 4
                for (int e = 0; e < 128; ++e) s += wr[e] * wih[e * 384 + n];
                v = s;
            } else if (k < 516) {
                const float* br = bm + ((k - 512) << 7);
                float s = 0.0f;
#pragma unroll 4
                for (int e = 0; e < 128; ++e) s += br[e] * wih[e * 384 + n];
                v = s;
            }
        } else {
            int kh = (kc - 17) * 32 + kin;  // 0..127
            int nlog = (gb < 2) ? gb * 128 + npart : 384 + npart;  // r,z,h_n
            int col = (nlog < 256) ? nlog : nlog - 128;            // w_hh col
            v = whh[kh * 384 + col];
        }
        W2f[idx] = __float2bfloat16(v);
        return;
    }
    int b = idx - W2F_N;
    if (b < NGATES) {
        float v;
        if (b < 256) v = bih[b] + bhh[b];
        else if (b < 384) v = bih[b];
        else v = bhh[b - 128];
        bias512[b] = v;
    }
}

// ---------------------------------------------------------------- per-type aggregation v3
// One WAVE per node; 4x 16-lane GROUPS walk the node's 4 type-lists CONCURRENTLY.
// Gather-chain collapse: lane sub loads csr_src[base+sub] (16 indices per instr),
// __shfl broadcasts index r to its group -> all h-row loads are address-independent
// and issue back-to-back (chain depth ~2 latencies instead of cnt).
__global__ __launch_bounds__(256) void k_agg(const __hip_bfloat16* __restrict__ hb,
                                             const int* __restrict__ off2,
                                             const int* __restrict__ csr_src,
                                             __hip_bfloat16* __restrict__ g) {
    const int node = (blockIdx.x * blockDim.x + threadIdx.x) >> 6;
    const int lane = threadIdx.x & 63;
    if (node >= NN) return;
    const int t = lane >> 4;      // group = etype
    const int sub = lane & 15;    // 8 dims per lane
    const int gbase = lane & 48;  // group's lane base for shfl
    const int p0 = off2[4 * node + t];
    const int p1 = off2[4 * node + t + 1];
    float a[8];
#pragma unroll
    for (int j = 0; j < 8; ++j) a[j] = 0.0f;
    for (int base = p0; base < p1; base += 16) {
        int cnt = p1 - base;
        if (cnt > 16) cnt = 16;
        int idxv = (sub < cnt) ? csr_src[base + sub] : 0;
        int r = 0;
        for (; r + 1 < cnt; r += 2) {
            int s0 = __shfl(idxv, gbase + r);
            int s1 = __shfl(idxv, gbase + r + 1);
            bf16x8 v0 = *(const bf16x8*)(hb + (size_t)s0 * DD + sub * 8);
            bf16x8 v1 = *(const bf16x8*)(hb + (size_t)s1 * DD + sub * 8);
#pragma unroll
            for (int j = 0; j < 8; ++j) a[j] += s2f(v0[j]) + s2f(v1[j]);
        }
        if (r < cnt) {
            int s0 = __shfl(idxv, gbase + r);
            bf16x8 v0 = *(const bf16x8*)(hb + (size_t)s0 * DD + sub * 8);
#pragma unroll
            for (int j = 0; j < 8; ++j) a[j] += s2f(v0[j]);
        }
    }
    bf16x8 o;
#pragma unroll
    for (int j = 0; j < 8; ++j) {
        __hip_bfloat16 b = __float2bfloat16(a[j]);
        o[j] = *(short*)&b;
    }
    *(bf16x8*)(g + (size_t)node * KAGG + t * 128 + sub * 8) = o;
}

// ---------------------------------------------------------------- fused step kernel (v7c)
// Round-15 structure (48.5 us) with the K-loop 2-chunk-unrolled: A in a 4x4KB ring,
// each iteration stages A(2j+2),A(2j+3), computes chunks 2j and 2j+1 (24 MFMA,
// B loads scoped per chunk so only 3 live at once), ONE barrier -> 11 barriers
// instead of 21. Buffer overwrite safety: As[(2j+2)&3] was last read in iteration
// j-1, protected by that iteration's barrier. Tail chunk 20 after the loop.
__global__ __launch_bounds__(512, 4) void k_step(const __hip_bfloat16* __restrict__ g,
                                                 const __hip_bfloat16* __restrict__ W2f,
                                                 const float* __restrict__ bias512,
                                                 const __hip_bfloat16* __restrict__ hbi,
                                                 __hip_bfloat16* __restrict__ hbo) {
    __shared__ __align__(16) short As[4][64 * 32];  // 4 x 4 KB ring
    __shared__ __align__(16) short Ht[64 * 132];    // 16.9 KB epilogue stage
    const int tid = threadIdx.x;
    const int lane = tid & 63;
    const int wave = tid >> 6;
    const int row0 = blockIdx.x * 64;
    const int quad = lane >> 4;
    const int m16 = lane & 15;
    const int koff = ((quad ^ ((m16 ^ (m16 >> 2)) & 3)) << 3);  // A swizzle (shorts)

    // A staging mapping (waves 0..3; slot = tid < 256)
    const int arow = tid >> 2;
    const int apart = (tid & 3) ^ ((arow ^ (arow >> 2)) & 3);
    int agrow = row0 + arow;
    if (agrow >= NN) agrow = NN - 1;
    const __hip_bfloat16* gA = g + (size_t)agrow * KAGG + apart * 8;
    const __hip_bfloat16* hA = hbi + (size_t)agrow * DD + apart * 8;
    const __hip_bfloat16* bw = W2f + ((size_t)(wave * 64 + lane)) * 8;  // own fragment base

    auto stage_A = [&](int kc) {
        if (wave < 4) {
            const glob_void* srcA = (kc < 17)
                                        ? (const glob_void*)(gA + kc * 32)
                                        : (const glob_void*)(hA + (kc - 17) * 32);
            __builtin_amdgcn_global_load_lds(srcA, (lds_void*)&As[kc & 3][(wave * 64) * 8],
                                             16, 0, 0);
        }
    };

    f32x4 acc[4][4];  // [row-tile][gate: r,z,in,hn]
#pragma unroll
    for (int rt = 0; rt < 4; ++rt)
#pragma unroll
        for (int c = 0; c < 4; ++c) acc[rt][c] = (f32x4){0.f, 0.f, 0.f, 0.f};

    // one chunk's worth of compute: B loads first (L2 latency heads the chain),
    // then af ds_reads, then 12 MFMAs.
    auto do_chunk = [&](int ki) {
        const __hip_bfloat16* bp = bw + ki * 12288;
        bf16x8 b0 = *(const bf16x8*)(bp);
        bf16x8 b1 = *(const bf16x8*)(bp + 4096);
        bf16x8 b2 = *(const bf16x8*)(bp + 8192);
        bf16x8 af[4];
#pragma unroll
        for (int rt = 0; rt < 4; ++rt)
            af[rt] = *(const bf16x8*)&As[ki & 3][(rt * 16 + m16) * 32 + koff];
#pragma unroll
        for (int rt = 0; rt < 4; ++rt)
            acc[rt][0] = __builtin_amdgcn_mfma_f32_16x16x32_bf16(af[rt], b0, acc[rt][0], 0, 0, 0);
#pragma unroll
        for (int rt = 0; rt < 4; ++rt)
            acc[rt][1] = __builtin_amdgcn_mfma_f32_16x16x32_bf16(af[rt], b1, acc[rt][1], 0, 0, 0);
        if (ki < 17) {
#pragma unroll
            for (int rt = 0; rt < 4; ++rt)
                acc[rt][2] = __builtin_amdgcn_mfma_f32_16x16x32_bf16(af[rt], b2, acc[rt][2], 0, 0, 0);
        } else {
#pragma unroll
            for (int rt = 0; rt < 4; ++rt)
                acc[rt][3] = __builtin_amdgcn_mfma_f32_16x16x32_bf16(af[rt], b2, acc[rt][3], 0, 0, 0);
        }
    };

    stage_A(0);
    stage_A(1);
    __syncthreads();

    for (int j = 0; j < 10; ++j) {
        const int k0 = 2 * j;
        if (k0 + 2 < 21) stage_A(k0 + 2);
        if (k0 + 3 < 21) stage_A(k0 + 3);
        do_chunk(k0);
        do_chunk(k0 + 1);
        __syncthreads();  // drains stage_A(k0+2/3); As[k0&3],As[(k0+1)&3] free next iter
    }
    do_chunk(20);  // staged in j=9; covered by its barrier

    // ---------------- epilogue: in-register GRU -> LDS (stride 132) -> full-line store
    {
        const int d = wave * 16 + m16;
        const float brs = bias512[d];
        const float bzs = bias512[128 + d];
        const float bin_ = bias512[256 + d];
        const float bhn = bias512[384 + d];
#pragma unroll
        for (int rt = 0; rt < 4; ++rt) {
#pragma unroll
            for (int j = 0; j < 4; ++j) {
                const int rowl = rt * 16 + quad * 4 + j;
                const int grow = row0 + rowl;
                const float rs = acc[rt][0][j] + brs;
                const float zs = acc[rt][1][j] + bzs;
                const float inn = acc[rt][2][j] + bin_;
                const float hnn = acc[rt][3][j] + bhn;
                const float rr = 1.0f / (1.0f + __expf(-rs));
                const float zz = 1.0f / (1.0f + __expf(-zs));
                const float ex = __expf(2.0f * (inn + rr * hnn));
                const float ng = 1.0f - 2.0f / (ex + 1.0f);  // tanh, overflow-safe
                const float hv =
                    bf2f(hbi[(size_t)(grow < NN ? grow : NN - 1) * DD + d]);
                const float o = (1.0f - zz) * ng + zz * hv;
                __hip_bfloat16 ob = __float2bfloat16(o);
                Ht[rowl * 132 + d] = *(short*)&ob;
            }
        }
    }
    __syncthreads();
    {
        // 512 threads x 32 B contiguous -> fully-coalesced full-line stores
        const int row = tid >> 3;
        const int col = (tid & 7) * 16;
        if (row0 + row < NN) {
            bf16x8 v0 = *(const bf16x8*)&Ht[row * 132 + col];
            bf16x8 v1 = *(const bf16x8*)&Ht[row * 132 + col + 8];
            __hip_bfloat16* dstp = hbo + (size_t)(row0 + row) * DD + col;
            *(bf16x8*)dstp = v0;
            *(bf16x8*)(dstp + 8) = v1;
        }
    }
}

// ---------------------------------------------------------------- readout (n2g is sorted)
__global__ __launch_bounds__(128) void k_readout(const __hip_bfloat16* __restrict__ h,
                                                 const float* __restrict__ h1,
                                                 const int* __restrict__ n2g,
                                                 float* __restrict__ feats) {
    const int CHN = 64;
    int d = threadIdx.x;
    int v0 = blockIdx.x * CHN;
    if (v0 >= NN) return;
    int v1 = v0 + CHN;
    if (v1 > NN) v1 = NN;
    float sum = 0.0f;
    int cur = n2g[v0];
    for (int v = v0; v < v1; ++v) {
        int gph = n2g[v];
        if (gph != cur) {
            atomicAdd(&feats[cur * DD + d], sum);
            sum = 0.0f;
            cur = gph;
        }
        sum += bf2f(h[(size_t)v * DD + d]) + h1[(size_t)v * DD + d];
    }
    atomicAdd(&feats[cur * DD + d], sum);
}

// ---------------------------------------------------------------- classifier
__global__ void k_cls(const float* __restrict__ feats, const float* __restrict__ Wc,
                      const float* __restrict__ bc, float* __restrict__ out) {
    int t = threadIdx.x;
    if (t >= BB * 2) return;
    int b = t >> 1, c = t & 1;
    float s = bc[c];
    for (int d = 0; d < DD; ++d) s += feats[b * DD + d] * Wc[d * 2 + c];
    out[t] = s;
}

// ================================================================ launcher
extern "C" void kernel_launch(void* const* d_in, const int* in_sizes, int n_in, void* d_out,
                              int out_size, void* d_ws, size_t ws_size, hipStream_t stream) {
    const float* features = (const float*)d_in[0];
    const int* src = (const int*)d_in[1];
    const int* dst = (const int*)d_in[2];
    const int* etype = (const int*)d_in[3];
    const int* n2g = (const int*)d_in[4];
    const float* W_msg = (const float*)d_in[5];
    const float* b_msg = (const float*)d_in[6];
    const float* w_ih = (const float*)d_in[7];
    const float* b_ih = (const float*)d_in[8];
    const float* w_hh = (const float*)d_in[9];
    const float* b_hh = (const float*)d_in[10];
    const float* W_cls = (const float*)d_in[11];
    const float* b_cls = (const float*)d_in[12];
    float* out = (float*)d_out;

    char* ws = (char*)d_ws;
    size_t o = 0;
    auto alloc = [&](size_t bytes) {
        o = (o + 255) & ~(size_t)255;
        void* p = ws + o;
        o += bytes;
        return p;
    };
    int* deg2 = (int*)alloc(sizeof(int) * NBIN);
    int* off2 = (int*)alloc(sizeof(int) * (NBIN + 1));
    int* cursor = (int*)alloc(sizeof(int) * NBIN);
    int* bsum = (int*)alloc(sizeof(int) * NBLK);
    int* boff = (int*)alloc(sizeof(int) * NBLK);
    int* csr_src = (int*)alloc(sizeof(int) * EE);
    __hip_bfloat16* W2f = (__hip_bfloat16*)alloc(sizeof(__hip_bfloat16) * W2F_N);
    float* bias512 = (float*)alloc(sizeof(float) * NGATES);
    float* hini = (float*)alloc(sizeof(float) * (size_t)NN * DD);
    __hip_bfloat16* hbfA = (__hip_bfloat16*)alloc(sizeof(__hip_bfloat16) * (size_t)NN * DD);
    __hip_bfloat16* hbfB = (__hip_bfloat16*)alloc(sizeof(__hip_bfloat16) * (size_t)NN * DD);
    __hip_bfloat16* g = (__hip_bfloat16*)alloc(sizeof(__hip_bfloat16) * (size_t)NN * KAGG);
    float* feats = (float*)alloc(sizeof(float) * BB * DD);

    // setup
    k_init_h<<<(NN * DD + 255) / 256, 256, 0, stream>>>(features, hini, hbfA);
    k_zero2<<<(NBIN + BB * DD + 255) / 256, 256, 0, stream>>>(deg2, feats);
    k_hist<<<(EE + 255) / 256, 256, 0, stream>>>(dst, etype, deg2);
    k_scan_bsum<<<NBLK, 256, 0, stream>>>(deg2, bsum);
    k_scan_boff<<<1, 1024, 0, stream>>>(bsum, boff);
    k_scan_final<<<NBLK, 256, 0, stream>>>(deg2, boff, off2, cursor, g);
    k_fill<<<(EE + 255) / 256, 256, 0, stream>>>(dst, src, etype, cursor, csr_src);
    {
        int prep_n = W2F_N + NGATES;
        k_prep_w2f<<<(prep_n + 255) / 256, 256, 0, stream>>>(W_msg, b_msg, w_ih, w_hh,
                                                             b_ih, b_hh, W2f, bias512);
    }

    __hip_bfloat16* hbc = hbfA;
    __hip_bfloat16* hbx = hbfB;
    for (int s = 0; s < STEPS; ++s) {
        k_agg<<<(NN * 64 + 255) / 256, 256, 0, stream>>>(hbc, off2, csr_src, g);
        k_step<<<MT64, 512, 0, stream>>>(g, W2f, bias512, hbc, hbx);
        __hip_bfloat16* tb = hbc; hbc = hbx; hbx = tb;
    }
    k_readout<<<(NN + 63) / 64, 128, 0, stream>>>(hbc, hini, n2g, feats);
    k_cls<<<1, 128, 0, stream>>>(feats, W_cls, b_cls, out);
}